// Round 3
// baseline (208.885 us; speedup 1.0000x reference)
//
#include <hip/hip_runtime.h>
#include <stdint.h>

typedef _Float16 half8 __attribute__((ext_vector_type(8)));
typedef float floatx4 __attribute__((ext_vector_type(4)));

#define KDIM   4096
#define ODIM   11008
#define NGROUP 32
#define K8     512   // qweight dwords per output row

// DT: 0 = fp32 delivery, 1 = fp16-packed, 2 = bf16-packed
template <int DT>
__device__ __forceinline__ void w4a16_body(
    const void*     __restrict__ xv,
    const uint32_t* __restrict__ qweight,
    const uint32_t* __restrict__ qzeros,
    const void*     __restrict__ sv,
    float*          __restrict__ out)
{
    const int t    = threadIdx.x;
    const int wv   = t >> 6;        // wave 0..3 -> M-tile
    const int lane = t & 63;
    const int q    = lane >> 4;     // quad 0..3 -> k-subblock (8 k each)
    const int ml   = lane & 15;

    const int o0 = blockIdx.x * 16;
    const int o  = o0 + ml;         // B fragment: n = lane&15
    const int gm = wv * 16 + ml;    // A fragment: m = lane&15

    const uint32_t* qwp = qweight + (size_t)o * K8 + q;

    const uint4 zr = *reinterpret_cast<const uint4*>(qzeros + (size_t)o * 4);
    const uint32_t zarr[4] = {zr.x, zr.y, zr.z, zr.w};

    floatx4 acc = {0.f, 0.f, 0.f, 0.f};

    #pragma unroll
    for (int gd = 0; gd < 4; ++gd) {
        const uint32_t zd = zarr[gd];
        for (int gi = 0; gi < 8; ++gi) {
            const int g = gd * 8 + gi;
            // exact fp16 integer (1024 + z)
            const uint16_t zb = (uint16_t)(0x6400u | ((zd >> (gi * 4)) & 0xFu));
            const _Float16 hz = __builtin_bit_cast(_Float16, zb);

            float s;
            if (DT == 0) {
                s = ((const float*)sv)[(size_t)o * NGROUP + g];
            } else {
                const uint16_t sb = ((const uint16_t*)sv)[(size_t)o * NGROUP + g];
                s = (DT == 1) ? (float)__builtin_bit_cast(_Float16, sb)
                              : __builtin_bit_cast(float, (uint32_t)sb << 16);
            }

            floatx4 tmp = {0.f, 0.f, 0.f, 0.f};
            #pragma unroll
            for (int ks = 0; ks < 4; ++ks) {
                const int kb = g * 128 + ks * 32;   // k offset of this frag chunk
                const size_t kidx = (size_t)gm * KDIM + q * 8 + kb;

                half8 a;
                if (DT == 0) {
                    const float4 f0 = *reinterpret_cast<const float4*>((const float*)xv + kidx);
                    const float4 f1 = *reinterpret_cast<const float4*>((const float*)xv + kidx + 4);
                    a[0] = (_Float16)f0.x; a[1] = (_Float16)f0.y;
                    a[2] = (_Float16)f0.z; a[3] = (_Float16)f0.w;
                    a[4] = (_Float16)f1.x; a[5] = (_Float16)f1.y;
                    a[6] = (_Float16)f1.z; a[7] = (_Float16)f1.w;
                } else {
                    const uint4 av = *reinterpret_cast<const uint4*>((const uint16_t*)xv + kidx);
                    const uint32_t aw[4] = {av.x, av.y, av.z, av.w};
                    #pragma unroll
                    for (int j = 0; j < 4; ++j) {
                        const uint16_t lo = (uint16_t)(aw[j] & 0xFFFFu);
                        const uint16_t hi = (uint16_t)(aw[j] >> 16);
                        if (DT == 1) {
                            a[2 * j]     = __builtin_bit_cast(_Float16, lo);
                            a[2 * j + 1] = __builtin_bit_cast(_Float16, hi);
                        } else {
                            a[2 * j]     = (_Float16)__builtin_bit_cast(float, (uint32_t)lo << 16);
                            a[2 * j + 1] = (_Float16)__builtin_bit_cast(float, (uint32_t)hi << 16);
                        }
                    }
                }

                const uint32_t u = qwp[g * 16 + ks * 4];
                half8 b;
                #pragma unroll
                for (int j = 0; j < 8; ++j) {
                    const uint16_t hb = (uint16_t)(0x6400u | ((u >> (4 * j)) & 0xFu));
                    b[j] = __builtin_bit_cast(_Float16, hb) - hz;   // exact (q - z)
                }

                tmp = __builtin_amdgcn_mfma_f32_16x16x32_f16(a, b, tmp, 0, 0, 0);
            }
            acc[0] += s * tmp[0];
            acc[1] += s * tmp[1];
            acc[2] += s * tmp[2];
            acc[3] += s * tmp[3];
        }
    }

    // C/D layout: col = lane&15 (o), row = quad*4 + reg  (m = wv*16 + q*4 + reg)
    float* orow = out + (size_t)(wv * 16 + q * 4) * ODIM + o;
    orow[0 * (size_t)ODIM] = acc[0];
    orow[1 * (size_t)ODIM] = acc[1];
    orow[2 * (size_t)ODIM] = acc[2];
    orow[3 * (size_t)ODIM] = acc[3];
}

__global__ __launch_bounds__(256) void w4a16_kernel(
    const void*     __restrict__ x,
    const uint32_t* __restrict__ qweight,
    const uint32_t* __restrict__ qzeros,
    const void*     __restrict__ scales,
    float*          __restrict__ out)
{
    // Wave-uniform dtype probe on scales (values are in [0.001, 0.02]).
    // bf16 bits of that range: [0x3A80, 0x3CB0]; fp16 bits: [0x1400, 0x2600].
    // fp32 delivery: high halves mimic bf16 but low halves are random mantissa.
    const uint32_t* sd = (const uint32_t*)scales;
    bool all_bf16 = true, all_fp16 = true;
    #pragma unroll
    for (int i = 0; i < 4; ++i) {
        const uint32_t d  = sd[i];
        const uint32_t lo = d & 0xFFFFu, hi = d >> 16;
        all_bf16 &= (lo >= 0x3A80u && lo <= 0x3CB0u) && (hi >= 0x3A80u && hi <= 0x3CB0u);
        all_fp16 &= (lo >= 0x1400u && lo <= 0x2600u) && (hi >= 0x1400u && hi <= 0x2600u);
    }
    if (all_bf16)
        w4a16_body<2>(x, qweight, qzeros, scales, out);
    else if (all_fp16)
        w4a16_body<1>(x, qweight, qzeros, scales, out);
    else
        w4a16_body<0>(x, qweight, qzeros, scales, out);
}

extern "C" void kernel_launch(void* const* d_in, const int* in_sizes, int n_in,
                              void* d_out, int out_size, void* d_ws, size_t ws_size,
                              hipStream_t stream) {
    const void*     x       = d_in[0];
    const uint32_t* qweight = (const uint32_t*)d_in[1];
    const uint32_t* qzeros  = (const uint32_t*)d_in[2];
    const void*     scales  = d_in[3];
    float* out = (float*)d_out;

    w4a16_kernel<<<dim3(ODIM / 16), dim3(256), 0, stream>>>(
        x, qweight, qzeros, scales, out);
}

// Round 5
// 121.194 us; speedup vs baseline: 1.7236x; 1.7236x over previous
//
#include <hip/hip_runtime.h>
#include <stdint.h>

typedef _Float16 half8  __attribute__((ext_vector_type(8)));
typedef _Float16 half2v __attribute__((ext_vector_type(2)));
typedef float    floatx4 __attribute__((ext_vector_type(4)));
typedef uint32_t uint4v  __attribute__((ext_vector_type(4)));

#define KDIM   4096
#define ODIM   11008
#define NG     32
#define K8     512      // qweight dwords per output row
#define KSPLIT 8
#define GPB    4        // groups (128 k) per k-chunk: 512 k per block
#define OBLK   172      // o-blocks of 64 columns: 172*64 = 11008

__global__ void zero_out_kernel(float4* __restrict__ out) {
    out[(size_t)blockIdx.x * 256 + threadIdx.x] = float4{0.f, 0.f, 0.f, 0.f};
}

__device__ __forceinline__ uint32_t pk_f16(float a, float b) {
    return __builtin_bit_cast(uint32_t, __builtin_amdgcn_cvt_pkrtz(a, b));
}

// Block: 256 thr = 4 waves. Wave wv: M-tile wv (16 rows) x 64 o-cols (4 subtiles).
// Grid: OBLK * KSPLIT = 1376 blocks; each block covers 512 k, atomic-accumulates.
// k-swizzle (consistent for A and B): hw slot (ks, quad q, j) <-> k = q*32+ks*8+j
// within each 128-k group, so qweight is one uint4/lane/group and x is 32
// consecutive floats/lane/group.
__global__ __launch_bounds__(256, 4) void w4a16_kernel(
    const float*    __restrict__ x,    // [64][4096] (fp32-upcast fp16)
    const uint32_t* __restrict__ qw,   // [11008][512]
    const uint32_t* __restrict__ qz,   // [11008][4]
    const float*    __restrict__ sc,   // [11008][32] (fp32-upcast fp16)
    float*          __restrict__ out)  // [64][11008]
{
    const int t    = threadIdx.x;
    const int wv   = t >> 6;
    const int lane = t & 63;
    const int q    = lane >> 4;
    const int ml   = lane & 15;

    const int ob = blockIdx.x % OBLK;
    const int kb = blockIdx.x / OBLK;
    const int o0 = ob * 64;
    const int g0 = kb * GPB;          // first group of this k-chunk
    const int m  = wv * 16 + ml;      // A fragment row

    const float*    xp  = x  + (size_t)m * KDIM + (size_t)g0 * 128 + q * 32;
    const uint32_t* qwp = qw + (size_t)(o0 + ml) * K8 + (size_t)g0 * 16 + q * 4;

    // Hoisted per-subtile zero dword (covers 8 groups >= our 4) and scales.
    uint32_t zdw[4];
    floatx4  svec[4];
    #pragma unroll
    for (int sub = 0; sub < 4; ++sub) {
        const int o = o0 + sub * 16 + ml;
        zdw[sub]  = qz[(size_t)o * 4 + (g0 >> 3)];
        svec[sub] = *reinterpret_cast<const floatx4*>(sc + (size_t)o * NG + g0);
    }
    const int zsh0 = (kb & 1) * 16;   // bit offset of group g0's nibble in zdw

    floatx4 acc[4] = {{0.f,0.f,0.f,0.f},{0.f,0.f,0.f,0.f},
                      {0.f,0.f,0.f,0.f},{0.f,0.f,0.f,0.f}};

    for (int g = 0; g < GPB; ++g) {
        // ---- A fragments: 32 consecutive floats -> 4 half8 (exact convert) ----
        half8 afrag[4];
        const float* xg = xp + g * 128;
        #pragma unroll
        for (int ks = 0; ks < 4; ++ks) {
            const float4 f0 = *reinterpret_cast<const float4*>(xg + ks * 8);
            const float4 f1 = *reinterpret_cast<const float4*>(xg + ks * 8 + 4);
            const uint4v aw = {pk_f16(f0.x, f0.y), pk_f16(f0.z, f0.w),
                               pk_f16(f1.x, f1.y), pk_f16(f1.z, f1.w)};
            afrag[ks] = __builtin_bit_cast(half8, aw);
        }

        // ---- 4 o-subtiles: one uint4 qweight load each, dequant, 4 MFMA ----
        #pragma unroll
        for (int sub = 0; sub < 4; ++sub) {
            const uint4v u = *reinterpret_cast<const uint4v*>(
                qwp + (size_t)sub * 16 * K8 + g * 16);

            const uint32_t zh = 0x6400u | ((zdw[sub] >> (zsh0 + g * 4)) & 0xFu);
            const half2v   cz = __builtin_bit_cast(half2v, zh | (zh << 16));
            const float    s  = svec[sub][g];

            floatx4 tmp = {0.f, 0.f, 0.f, 0.f};
            #pragma unroll
            for (int ks = 0; ks < 4; ++ks) {
                const uint32_t ud = u[ks];
                const uint32_t t0 = ( ud        & 0x000F000Fu) | 0x64006400u; // n0,n4
                const uint32_t t1 = ((ud >> 4)  & 0x000F000Fu) | 0x64006400u; // n1,n5
                const uint32_t t2 = ((ud >> 8)  & 0x000F000Fu) | 0x64006400u; // n2,n6
                const uint32_t t3 = ((ud >> 12) & 0x000F000Fu) | 0x64006400u; // n3,n7
                const uint32_t p0 = __builtin_amdgcn_perm(t1, t0, 0x05040100u); // n0,n1
                const uint32_t p1 = __builtin_amdgcn_perm(t3, t2, 0x05040100u); // n2,n3
                const uint32_t p2 = __builtin_amdgcn_perm(t1, t0, 0x07060302u); // n4,n5
                const uint32_t p3 = __builtin_amdgcn_perm(t3, t2, 0x07060302u); // n6,n7
                const half2v w0 = __builtin_bit_cast(half2v, p0) - cz; // exact q-z
                const half2v w1 = __builtin_bit_cast(half2v, p1) - cz;
                const half2v w2 = __builtin_bit_cast(half2v, p2) - cz;
                const half2v w3 = __builtin_bit_cast(half2v, p3) - cz;
                const uint4v bw = {__builtin_bit_cast(uint32_t, w0),
                                   __builtin_bit_cast(uint32_t, w1),
                                   __builtin_bit_cast(uint32_t, w2),
                                   __builtin_bit_cast(uint32_t, w3)};
                const half8 b = __builtin_bit_cast(half8, bw);
                tmp = __builtin_amdgcn_mfma_f32_16x16x32_f16(afrag[ks], b, tmp, 0, 0, 0);
            }
            acc[sub][0] += s * tmp[0];
            acc[sub][1] += s * tmp[1];
            acc[sub][2] += s * tmp[2];
            acc[sub][3] += s * tmp[3];
        }
    }

    // C/D layout: col = lane&15, row = q*4 + reg; accumulate across k-chunks.
    const int mrow = wv * 16 + q * 4;
    #pragma unroll
    for (int sub = 0; sub < 4; ++sub) {
        float* op = out + (size_t)mrow * ODIM + (o0 + sub * 16 + ml);
        atomicAdd(op,                  acc[sub][0]);
        atomicAdd(op + (size_t)ODIM,   acc[sub][1]);
        atomicAdd(op + 2*(size_t)ODIM, acc[sub][2]);
        atomicAdd(op + 3*(size_t)ODIM, acc[sub][3]);
    }
}

extern "C" void kernel_launch(void* const* d_in, const int* in_sizes, int n_in,
                              void* d_out, int out_size, void* d_ws, size_t ws_size,
                              hipStream_t stream) {
    const float*    x       = (const float*)d_in[0];
    const uint32_t* qweight = (const uint32_t*)d_in[1];
    const uint32_t* qzeros  = (const uint32_t*)d_in[2];
    const float*    scales  = (const float*)d_in[3];
    float* out = (float*)d_out;

    // 64*11008 floats = 176128 float4 = 688 blocks * 256 threads
    zero_out_kernel<<<dim3(688), dim3(256), 0, stream>>>((float4*)out);
    w4a16_kernel<<<dim3(OBLK * KSPLIT), dim3(256), 0, stream>>>(
        x, qweight, qzeros, scales, out);
}

// Round 6
// 110.068 us; speedup vs baseline: 1.8978x; 1.1011x over previous
//
#include <hip/hip_runtime.h>
#include <stdint.h>

typedef _Float16 half8  __attribute__((ext_vector_type(8)));
typedef _Float16 half2v __attribute__((ext_vector_type(2)));
typedef float    floatx4 __attribute__((ext_vector_type(4)));
typedef uint32_t uint4v  __attribute__((ext_vector_type(4)));

#define KDIM   4096
#define ODIM   11008
#define NG     32
#define K8     512      // qweight dwords per output row
#define KU     (KDIM/8) // x_f16 row length in uint4 units (8 f16 each) = 512
#define KSPLIT 8
#define GPB    4        // groups (128 k) per k-chunk: 512 k per block
#define OBLK   172      // o-blocks of 64 columns: 172*64 = 11008

__global__ void zero_out_kernel(float4* __restrict__ out) {
    out[(size_t)blockIdx.x * 256 + threadIdx.x] = float4{0.f, 0.f, 0.f, 0.f};
}

__device__ __forceinline__ uint32_t pk_f16(float a, float b) {
    return __builtin_bit_cast(uint32_t, __builtin_amdgcn_cvt_pkrtz(a, b));
}

// x fp32 [64][4096] -> fp16 packed into d_ws. 32768 threads x 8 floats.
__global__ __launch_bounds__(256) void cvt_x_kernel(
    const float4* __restrict__ x, uint4v* __restrict__ xh)
{
    const size_t i = (size_t)blockIdx.x * 256 + threadIdx.x;
    const float4 f0 = x[2 * i];
    const float4 f1 = x[2 * i + 1];
    xh[i] = uint4v{pk_f16(f0.x, f0.y), pk_f16(f0.z, f0.w),
                   pk_f16(f1.x, f1.y), pk_f16(f1.z, f1.w)};
}

struct GBuf { uint4v a[4]; uint4v u[4]; };   // x frags (4x8 f16) + qweight (4 subs)

// Block: 256 thr = 4 waves. Wave wv: M-tile wv (16 rows) x 64 o-cols (4 subtiles).
// Grid: OBLK * KSPLIT = 1376 blocks; block covers 512 k, atomic-accumulates.
// k-swizzle (consistent A/B): hw slot (ks, quad q, j) <-> k = q*32+ks*8+j within
// each 128-k group -> qweight one uint4/lane/(group,sub), x 4 uint4/lane/group.
__global__ __launch_bounds__(256, 4) void w4a16_kernel(
    const uint4v*   __restrict__ xh,   // [64][512] packed f16
    const uint32_t* __restrict__ qw,   // [11008][512]
    const uint32_t* __restrict__ qz,   // [11008][4]
    const float*    __restrict__ sc,   // [11008][32] (fp32-upcast fp16)
    float*          __restrict__ out)  // [64][11008]
{
    const int t    = threadIdx.x;
    const int wv   = t >> 6;
    const int lane = t & 63;
    const int q    = lane >> 4;
    const int ml   = lane & 15;

    const int ob = blockIdx.x % OBLK;
    const int kb = blockIdx.x / OBLK;
    const int o0 = ob * 64;
    const int g0 = kb * GPB;
    const int m  = wv * 16 + ml;

    const uint4v*   xp  = xh + (size_t)m * KU + (size_t)g0 * 16 + q * 4;
    const uint32_t* qwp = qw + (size_t)(o0 + ml) * K8 + (size_t)g0 * 16 + q * 4;

    // Hoisted per-subtile zero dword (covers 8 groups >= our 4) and scales.
    uint32_t zdw[4];
    floatx4  svec[4];
    #pragma unroll
    for (int sub = 0; sub < 4; ++sub) {
        const int o = o0 + sub * 16 + ml;
        zdw[sub]  = qz[(size_t)o * 4 + (g0 >> 3)];
        svec[sub] = *reinterpret_cast<const floatx4*>(sc + (size_t)o * NG + g0);
    }
    const int zsh0 = (kb & 1) * 16;   // bit offset of group g0's nibble in zdw

    floatx4 acc[4] = {{0.f,0.f,0.f,0.f},{0.f,0.f,0.f,0.f},
                      {0.f,0.f,0.f,0.f},{0.f,0.f,0.f,0.f}};

    GBuf buf[2];

    // ---- load for group g into buffer ----
    auto load_g = [&](int g, GBuf& B) {
        #pragma unroll
        for (int ks = 0; ks < 4; ++ks)
            B.a[ks] = xp[g * 16 + ks];
        #pragma unroll
        for (int sub = 0; sub < 4; ++sub)
            B.u[sub] = *reinterpret_cast<const uint4v*>(
                qwp + (size_t)sub * 16 * K8 + g * 16);
    };

    load_g(0, buf[0]);

    #pragma unroll
    for (int g = 0; g < GPB; ++g) {
        if (g + 1 < GPB) load_g(g + 1, buf[(g + 1) & 1]);
        GBuf& B = buf[g & 1];

        half8 afrag[4];
        #pragma unroll
        for (int ks = 0; ks < 4; ++ks)
            afrag[ks] = __builtin_bit_cast(half8, B.a[ks]);

        #pragma unroll
        for (int sub = 0; sub < 4; ++sub) {
            const uint32_t zh = 0x6400u | ((zdw[sub] >> (zsh0 + g * 4)) & 0xFu);
            const half2v   cz = __builtin_bit_cast(half2v, zh | (zh << 16));
            const float    s  = svec[sub][g];

            floatx4 tmp = {0.f, 0.f, 0.f, 0.f};
            #pragma unroll
            for (int ks = 0; ks < 4; ++ks) {
                const uint32_t ud = B.u[sub][ks];
                const uint32_t t0 = ( ud        & 0x000F000Fu) | 0x64006400u; // n0,n4
                const uint32_t t1 = ((ud >> 4)  & 0x000F000Fu) | 0x64006400u; // n1,n5
                const uint32_t t2 = ((ud >> 8)  & 0x000F000Fu) | 0x64006400u; // n2,n6
                const uint32_t t3 = ((ud >> 12) & 0x000F000Fu) | 0x64006400u; // n3,n7
                const uint32_t p0 = __builtin_amdgcn_perm(t1, t0, 0x05040100u); // n0,n1
                const uint32_t p1 = __builtin_amdgcn_perm(t3, t2, 0x05040100u); // n2,n3
                const uint32_t p2 = __builtin_amdgcn_perm(t1, t0, 0x07060302u); // n4,n5
                const uint32_t p3 = __builtin_amdgcn_perm(t3, t2, 0x07060302u); // n6,n7
                const half2v w0 = __builtin_bit_cast(half2v, p0) - cz; // exact q-z
                const half2v w1 = __builtin_bit_cast(half2v, p1) - cz;
                const half2v w2 = __builtin_bit_cast(half2v, p2) - cz;
                const half2v w3 = __builtin_bit_cast(half2v, p3) - cz;
                const uint4v bw = {__builtin_bit_cast(uint32_t, w0),
                                   __builtin_bit_cast(uint32_t, w1),
                                   __builtin_bit_cast(uint32_t, w2),
                                   __builtin_bit_cast(uint32_t, w3)};
                const half8 b = __builtin_bit_cast(half8, bw);
                tmp = __builtin_amdgcn_mfma_f32_16x16x32_f16(afrag[ks], b, tmp, 0, 0, 0);
            }
            acc[sub][0] += s * tmp[0];
            acc[sub][1] += s * tmp[1];
            acc[sub][2] += s * tmp[2];
            acc[sub][3] += s * tmp[3];
        }
    }

    // C/D layout: col = lane&15, row = q*4 + reg; accumulate across k-chunks.
    const int mrow = wv * 16 + q * 4;
    #pragma unroll
    for (int sub = 0; sub < 4; ++sub) {
        float* op = out + (size_t)mrow * ODIM + (o0 + sub * 16 + ml);
        atomicAdd(op,                  acc[sub][0]);
        atomicAdd(op + (size_t)ODIM,   acc[sub][1]);
        atomicAdd(op + 2*(size_t)ODIM, acc[sub][2]);
        atomicAdd(op + 3*(size_t)ODIM, acc[sub][3]);
    }
}

extern "C" void kernel_launch(void* const* d_in, const int* in_sizes, int n_in,
                              void* d_out, int out_size, void* d_ws, size_t ws_size,
                              hipStream_t stream) {
    const float*    x       = (const float*)d_in[0];
    const uint32_t* qweight = (const uint32_t*)d_in[1];
    const uint32_t* qzeros  = (const uint32_t*)d_in[2];
    const float*    scales  = (const float*)d_in[3];
    float* out = (float*)d_out;
    uint4v* xh = (uint4v*)d_ws;        // 64*4096 f16 = 512 KB scratch

    // x fp32 -> f16: 262144 floats / 8 per thread = 32768 thr = 128 blocks
    cvt_x_kernel<<<dim3(128), dim3(256), 0, stream>>>((const float4*)x, xh);
    // zero out: 64*11008 floats = 176128 float4 = 688 blocks * 256 threads
    zero_out_kernel<<<dim3(688), dim3(256), 0, stream>>>((float4*)out);
    w4a16_kernel<<<dim3(OBLK * KSPLIT), dim3(256), 0, stream>>>(
        xh, qweight, qzeros, scales, out);
}